// Round 7
// baseline (174.730 us; speedup 1.0000x reference)
//
#include <hip/hip_runtime.h>

// GCN 2-layer forward — 8-dispatch (+4KB memset) pipeline.
// Session rules: dispatch boundary ~1us (R9); grid.sync ~70us (R8); spin
// barriers serialize (R10); serial global loops are latency poison (R11);
// BULK (100K+) random device atomics are poison, ~20K fine (R18); gathers
// are VALU/VMEM-ISSUE bound, not L2-fill bound (R17); fp8 excluded (R13).
// R19 (189.6): operand-swapped gemm1 -> dwordx2 stores. R20 (172.1, WIN):
// hist->gh atomics (scanB serial reduce deleted) + 512-thr partition/bsort.
// R21: per-edge instruction diet.
//   a) srec[e] = src | bf16(dinv[src])<<16 (built by k_wgt after bsort):
//      kills the per-edge dinv gather in BOTH pulls; dinv[dst] folded into
//      epilogue fmaf.
//   b) pullg: uint4 h-loads, 16 lanes/node, 4 nodes/wave (one wave-load =
//      4 full 256B rows, coalesced); gemm2 epilogue uses all 256 thr.
//   c) pull2: 4 thr/node x 4 classes (uint2) -> edge re-walk 8E -> 4E.
// Pipeline: memset(gh) -> combo(gemm1 MFMA || hist->gh) -> scanB ->
//           partition -> bsort -> wgt -> pullg -> pull2+lsm

typedef unsigned int uint32;
typedef unsigned short u16;
typedef __attribute__((ext_vector_type(8))) short bf16x8;
typedef __attribute__((ext_vector_type(4))) float f32x4;

#define NBMAX 1024
#define CHUNK 4096
#define EH 8192   // edges per hist block

__device__ inline u16 bf16rn(float f) {
    unsigned u = __float_as_uint(f);
    return (u16)((u + 0x7fffu + ((u >> 16) & 1u)) >> 16);
}

__device__ inline void bffma(float2& a, float w, uint32 u) {
    a.x = fmaf(w, __uint_as_float(u << 16), a.x);
    a.y = fmaf(w, __uint_as_float(u & 0xffff0000u), a.y);
}

// ---- L1: gemm1 tiles || hist blocks (LDS hist -> global gh atomics) -------
__global__ __launch_bounds__(256) void k_combo(
    const float* __restrict__ x, const float* __restrict__ W1,
    const int* __restrict__ dstv, int* __restrict__ gh,
    u16* __restrict__ h, int N, int E, int NB, int ntile)
{
    __shared__ __align__(16) unsigned char smem[128 * 136 * 2];  // 34816 B
    int t = threadIdx.x;

    if ((int)blockIdx.x >= ntile) {
        int* hl = (int*)smem;
        int hb = blockIdx.x - ntile;
        int e0 = hb * EH, e1 = min(e0 + EH, E);
        for (int i = t; i < NB; i += 256) hl[i] = 0;
        __syncthreads();
        for (int e = e0 + t; e < e1; e += 256)
            atomicAdd(&hl[dstv[e] >> 8], 1);
        __syncthreads();
        for (int i = t; i < NB; i += 256) {
            int c = hl[i];
            if (c) atomicAdd(&gh[i], c);   // ~196 device atomics/block (cheap)
        }
        return;
    }

    // gemm1: h[N,128](bf16) = x @ W1, MFMA 16x16x32, operands swapped:
    // D[feature][node]; lane owns node=rowbase+ln, features ct*16+quad*4+i.
    u16* Wl = (u16*)smem;  // [n][k] pitch 136 (2-way bank aliasing: free)
    const float4* Wg4 = (const float4*)W1;
    for (int g = t; g < 128 * 32; g += 256) {
        int k = g >> 5, n4 = (g & 31) * 4;
        float4 v = Wg4[g];
        Wl[(n4 + 0) * 136 + k] = bf16rn(v.x);
        Wl[(n4 + 1) * 136 + k] = bf16rn(v.y);
        Wl[(n4 + 2) * 136 + k] = bf16rn(v.z);
        Wl[(n4 + 3) * 136 + k] = bf16rn(v.w);
    }
    __syncthreads();

    int wave = t >> 6, lane = t & 63;
    int quad = lane >> 4, ln = lane & 15;
    int rowbase = blockIdx.x * 64 + wave * 16;
    int node = rowbase + ln;
    int rclamp = min(node, N - 1);

    f32x4 acc[8];
    #pragma unroll
    for (int ct = 0; ct < 8; ++ct) acc[ct] = (f32x4){0.f, 0.f, 0.f, 0.f};

    #pragma unroll
    for (int q = 0; q < 4; ++q) {
        const float4* xr = (const float4*)(x + (size_t)rclamp * 128 + q * 32 + quad * 8);
        float4 a0 = xr[0], a1 = xr[1];
        bf16x8 xfr;   // B-operand: col=node(ln), k = q*32 + quad*8 + e
        xfr[0] = (short)bf16rn(a0.x); xfr[1] = (short)bf16rn(a0.y);
        xfr[2] = (short)bf16rn(a0.z); xfr[3] = (short)bf16rn(a0.w);
        xfr[4] = (short)bf16rn(a1.x); xfr[5] = (short)bf16rn(a1.y);
        xfr[6] = (short)bf16rn(a1.z); xfr[7] = (short)bf16rn(a1.w);
        #pragma unroll
        for (int ct = 0; ct < 8; ++ct) {
            // A-operand: row=feature-in-block(ln), k = q*32 + quad*8 + e
            bf16x8 wfr = *(const bf16x8*)&Wl[(ct * 16 + ln) * 136 + q * 32 + quad * 8];
            acc[ct] = __builtin_amdgcn_mfma_f32_16x16x32_bf16(wfr, xfr, acc[ct], 0, 0, 0);
        }
    }
    if (node < N) {
        u16* hp = h + (size_t)node * 128 + quad * 4;
        #pragma unroll
        for (int ct = 0; ct < 8; ++ct) {
            uint2 v;
            v.x = (uint32)bf16rn(acc[ct][0]) | ((uint32)bf16rn(acc[ct][1]) << 16);
            v.y = (uint32)bf16rn(acc[ct][2]) | ((uint32)bf16rn(acc[ct][3]) << 16);
            *(uint2*)(hp + ct * 16) = v;
        }
    }
}

// ---- L2: exclusive scan of gh, zero bfill ---------------------------------
__global__ __launch_bounds__(1024) void k_scanB(
    const int* __restrict__ gh, int* __restrict__ bbase,
    int* __restrict__ bfill, int NB, int E)
{
    __shared__ int s[1024];
    int t = threadIdx.x;
    int v = (t < NB) ? gh[t] : 0;
    s[t] = v;
    __syncthreads();
    for (int off = 1; off < 1024; off <<= 1) {
        int u = (t >= off) ? s[t - off] : 0;
        __syncthreads();
        s[t] += u;
        __syncthreads();
    }
    if (t < NB) {
        bbase[t] = s[t] - v;
        bfill[t] = 0;
    }
    if (t == 0) bbase[NB] = E;
}

// ---- L3: partition edges into bucket regions (512 threads/block) ----------
__global__ __launch_bounds__(512) void k_partition(
    const int* __restrict__ src, const int* __restrict__ dstv,
    const int* __restrict__ bbase, int* __restrict__ bfill,
    uint32* __restrict__ tmp, int E, int NB)
{
    __shared__ int cntL[NBMAX];
    __shared__ int baseL[NBMAX];
    int t = threadIdx.x;
    int e0 = blockIdx.x * CHUNK;
    int e1 = min(e0 + CHUNK, E);
    for (int i = t; i < NB; i += 512) cntL[i] = 0;
    __syncthreads();
    for (int e = e0 + t; e < e1; e += 512)
        atomicAdd(&cntL[dstv[e] >> 8], 1);
    __syncthreads();
    for (int i = t; i < NB; i += 512) {
        int cc = cntL[i];
        baseL[i] = cc ? bbase[i] + atomicAdd(&bfill[i], cc) : 0;
        cntL[i] = 0;
    }
    __syncthreads();
    for (int e = e0 + t; e < e1; e += 512) {
        int sv = src[e], d = dstv[e];
        int b = d >> 8;
        int r = atomicAdd(&cntL[b], 1);
        tmp[baseL[b] + r] = (uint32)sv | ((uint32)(d & 255) << 16);
    }
}

// ---- L4: per-bucket exact sort (512 threads); emit dinv / rs / srec -------
__global__ __launch_bounds__(512) void k_bsort(
    const uint32* __restrict__ tmp, const int* __restrict__ bbase,
    uint32* __restrict__ srec, int* __restrict__ rs,
    float* __restrict__ dinv, int N)
{
    __shared__ int cnt[256];
    __shared__ int ofs[256];
    int t = threadIdx.x;
    int b = blockIdx.x;
    int base = bbase[b];
    int endb = bbase[b + 1];
    int node0 = b << 8;

    if (t < 256) cnt[t] = 0;
    __syncthreads();
    for (int i = base + t; i < endb; i += 512)
        atomicAdd(&cnt[(tmp[i] >> 16) & 255], 1);
    __syncthreads();
    int v = (t < 256) ? cnt[t] : 0;
    __syncthreads();
    for (int off = 1; off < 256; off <<= 1) {
        int u = (t >= off && t < 256) ? cnt[t - off] : 0;
        __syncthreads();
        if (t < 256) cnt[t] += u;
        __syncthreads();
    }
    if (t < 256) {
        int node = node0 + t;
        if (node < N) {
            dinv[node] = rsqrtf(fmaxf((float)v, 1.0f));
            rs[node] = base + cnt[t];
        }
        ofs[t] = base + cnt[t] - v;
    }
    __syncthreads();
    for (int i = base + t; i < endb; i += 512) {
        uint32 rec = tmp[i];
        int pos = atomicAdd(&ofs[(rec >> 16) & 255], 1);
        srec[pos] = rec & 0xffffu;
    }
}

// ---- L4b: patch bf16(dinv[src]) into srec high bits -----------------------
__global__ __launch_bounds__(256) void k_wgt(
    uint32* __restrict__ srec, const float* __restrict__ dinv, int E)
{
    int i = blockIdx.x * 256 + threadIdx.x;
    if (i >= E) return;
    uint32 s = srec[i] & 0xffffu;
    srec[i] = s | ((uint32)bf16rn(dinv[s]) << 16);
}

// ---- L5: pullg — fused pull1 + gemm2; uint4 rows, rec-weights -------------
__global__ __launch_bounds__(256) void k_pullg(
    const int* __restrict__ rs, const uint32* __restrict__ srec,
    const float* __restrict__ dinv, const uint4* __restrict__ h4,
    const float* __restrict__ b1, const float* __restrict__ W2,
    u16* __restrict__ h2, int N)
{
    __shared__ float W2T[16 * 132];    // [f][k] pitch 132
    __shared__ float rowbuf[16 * 132]; // [r][k] pitch 132 (float4 pitch 33)
    int t = threadIdx.x;

    for (int g = t; g < 2048; g += 256) {
        int k = g >> 4, f = g & 15;
        W2T[f * 132 + k] = W2[g];
    }

    int wave = t >> 6, lane = t & 63;
    int rr = lane >> 4;                // node within wave (0..3)
    int rl = lane & 15;                // 16B chunk (8 feats) within row
    int rowbase = blockIdx.x * 16;
    int n = rowbase + wave * 4 + rr;
    bool valid = (n < N);
    int nc = valid ? n : 0;
    int start = valid ? ((nc == 0) ? 0 : rs[nc - 1]) : 0;
    int len   = valid ? (rs[nc] - start) : 0;
    float dn  = valid ? dinv[nc] : 0.f;
    int m = max(len, __shfl_xor(len, 16));
    m = max(m, __shfl_xor(m, 32));

    float2 aA[4], aB[4], aC[4], aD[4];
    #pragma unroll
    for (int k = 0; k < 4; ++k) {
        aA[k] = (float2){0.f, 0.f}; aB[k] = (float2){0.f, 0.f};
        aC[k] = (float2){0.f, 0.f}; aD[k] = (float2){0.f, 0.f};
    }

    for (int tt = 0; tt < m; tt += 4) {
        uint32 rec[4];
        uint4 u[4];
        float w[4];
        #pragma unroll
        for (int k = 0; k < 4; ++k) {
            bool act = (tt + k) < len;
            int jj = act ? (start + tt + k) : 0;   // index 0 always valid
            rec[k] = srec[jj];
            w[k] = act ? 1.f : 0.f;
        }
        #pragma unroll
        for (int k = 0; k < 4; ++k)
            u[k] = h4[(size_t)(rec[k] & 0xffffu) * 16 + rl];
        #pragma unroll
        for (int k = 0; k < 4; ++k)
            w[k] *= __uint_as_float(rec[k] & 0xffff0000u);  // bf16 dinv[src]
        #pragma unroll
        for (int k = 0; k < 4; ++k) {
            bffma(aA[k], w[k], u[k].x);
            bffma(aB[k], w[k], u[k].y);
            bffma(aC[k], w[k], u[k].z);
            bffma(aD[k], w[k], u[k].w);
        }
    }

    {
        int r = wave * 4 + rr;
        float4 b0 = ((const float4*)b1)[rl * 2];
        float4 b4 = ((const float4*)b1)[rl * 2 + 1];
        float4 v0, v1;
        v0.x = fmaxf(fmaf(dn, (aA[0].x + aA[1].x) + (aA[2].x + aA[3].x), b0.x), 0.f);
        v0.y = fmaxf(fmaf(dn, (aA[0].y + aA[1].y) + (aA[2].y + aA[3].y), b0.y), 0.f);
        v0.z = fmaxf(fmaf(dn, (aB[0].x + aB[1].x) + (aB[2].x + aB[3].x), b0.z), 0.f);
        v0.w = fmaxf(fmaf(dn, (aB[0].y + aB[1].y) + (aB[2].y + aB[3].y), b0.w), 0.f);
        v1.x = fmaxf(fmaf(dn, (aC[0].x + aC[1].x) + (aC[2].x + aC[3].x), b4.x), 0.f);
        v1.y = fmaxf(fmaf(dn, (aC[0].y + aC[1].y) + (aC[2].y + aC[3].y), b4.y), 0.f);
        v1.z = fmaxf(fmaf(dn, (aD[0].x + aD[1].x) + (aD[2].x + aD[3].x), b4.z), 0.f);
        v1.w = fmaxf(fmaf(dn, (aD[0].y + aD[1].y) + (aD[2].y + aD[3].y), b4.w), 0.f);
        ((float4*)rowbuf)[r * 33 + rl * 2] = v0;
        ((float4*)rowbuf)[r * 33 + rl * 2 + 1] = v1;
    }
    __syncthreads();

    {
        int f = t & 15, r = t >> 4;
        const float4* W4 = (const float4*)W2T;
        const float4* rb4 = (const float4*)rowbuf;
        float acc = 0.f;
        #pragma unroll 8
        for (int k4 = 0; k4 < 32; ++k4) {
            float4 w = W4[f * 33 + k4];
            float4 xv = rb4[r * 33 + k4];
            acc = fmaf(xv.x, w.x, acc);
            acc = fmaf(xv.y, w.y, acc);
            acc = fmaf(xv.z, w.z, acc);
            acc = fmaf(xv.w, w.w, acc);
        }
        int rn = rowbase + r;
        if (rn < N) h2[(size_t)rn * 16 + f] = bf16rn(acc);
    }
}

// ---- L6: pull2 + log_softmax — 4 thr/node x 4 classes, rec-weights --------
__global__ __launch_bounds__(256) void k_pull2(
    const int* __restrict__ rs, const uint32* __restrict__ srec,
    const float* __restrict__ dinv, const uint2* __restrict__ h2,
    const float* __restrict__ b2, float* __restrict__ out, int N)
{
    int idx = blockIdx.x * 256 + threadIdx.x;
    int n = idx >> 2;
    if (n >= N) return;
    int c4 = idx & 3;                  // classes [c4*4, c4*4+4)
    int start = (n == 0) ? 0 : rs[n - 1];
    int len = rs[n] - start;
    float dn = dinv[n];

    float2 aX[4], aY[4];
    #pragma unroll
    for (int k = 0; k < 4; ++k) {
        aX[k] = (float2){0.f, 0.f};
        aY[k] = (float2){0.f, 0.f};
    }

    for (int tt = 0; tt < len; tt += 4) {
        uint32 rec[4];
        uint2 u[4];
        float w[4];
        #pragma unroll
        for (int k = 0; k < 4; ++k) {
            bool act = (tt + k) < len;
            int jj = act ? (start + tt + k) : 0;   // index 0 always valid
            rec[k] = srec[jj];
            w[k] = act ? 1.f : 0.f;
        }
        #pragma unroll
        for (int k = 0; k < 4; ++k)
            u[k] = h2[(size_t)(rec[k] & 0xffffu) * 4 + c4];
        #pragma unroll
        for (int k = 0; k < 4; ++k)
            w[k] *= __uint_as_float(rec[k] & 0xffff0000u);
        #pragma unroll
        for (int k = 0; k < 4; ++k) {
            bffma(aX[k], w[k], u[k].x);
            bffma(aY[k], w[k], u[k].y);
        }
    }

    float4 bb = ((const float4*)b2)[c4];
    float v0 = fmaf(dn, (aX[0].x + aX[1].x) + (aX[2].x + aX[3].x), bb.x);
    float v1 = fmaf(dn, (aX[0].y + aX[1].y) + (aX[2].y + aX[3].y), bb.y);
    float v2 = fmaf(dn, (aY[0].x + aY[1].x) + (aY[2].x + aY[3].x), bb.z);
    float v3 = fmaf(dn, (aY[0].y + aY[1].y) + (aY[2].y + aY[3].y), bb.w);
    float mx = fmaxf(fmaxf(v0, v1), fmaxf(v2, v3));
    mx = fmaxf(mx, __shfl_xor(mx, 1));
    mx = fmaxf(mx, __shfl_xor(mx, 2));
    float s = expf(v0 - mx) + expf(v1 - mx) + expf(v2 - mx) + expf(v3 - mx);
    s += __shfl_xor(s, 1);
    s += __shfl_xor(s, 2);
    float ls = logf(s);
    float4 r = {v0 - mx - ls, v1 - mx - ls, v2 - mx - ls, v3 - mx - ls};
    ((float4*)out)[(size_t)n * 4 + c4] = r;
}

extern "C" void kernel_launch(void* const* d_in, const int* in_sizes, int n_in,
                              void* d_out, int out_size, void* d_ws, size_t ws_size,
                              hipStream_t stream) {
    const float* x  = (const float*)d_in[0];
    const int*   ei = (const int*)d_in[1];
    const float* W1 = (const float*)d_in[2];
    const float* b1 = (const float*)d_in[3];
    const float* W2 = (const float*)d_in[4];
    const float* b2 = (const float*)d_in[5];
    float* outp = (float*)d_out;

    const int E = in_sizes[1] / 2;
    const int N = in_sizes[0] / 128;   // N=50000 (fits u16 src packing)
    const int NB = (N + 255) >> 8;
    const int NH = (E + EH - 1) / EH;
    const int ntile = (N + 63) / 64;
    const int* src  = ei;
    const int* dstv = ei + E;

    const int Npad = (N + 255) & ~255;
    const int Epad = (E + 255) & ~255;
    int*   gh    = (int*)d_ws;                      // [NBMAX] global hist
    int*   bbase = gh + NBMAX;                      // [NBMAX+1] (+pad)
    int*   bfill = bbase + NBMAX + 256;             // [NBMAX]
    int*   rs    = bfill + NBMAX;                   // [Npad]
    float* dinv  = (float*)(rs + Npad);             // [Npad]
    uint32* tmp  = (uint32*)(dinv + Npad);          // [Epad] packed src|dstlow
    uint32* srec = tmp + Epad;                      // [Epad] src | bf16(dinv)<<16
    uintptr_t hp = ((uintptr_t)(srec + Epad) + 255) & ~(uintptr_t)255;
    u16*   h     = (u16*)hp;                        // [Npad*128] bf16
    u16*   h2    = h + (size_t)Npad * 128;          // [Npad*16] bf16

    hipMemsetAsync(gh, 0, NBMAX * sizeof(int), stream);
    k_combo<<<ntile + NH, 256, 0, stream>>>(x, W1, dstv, gh, h, N, E, NB, ntile);
    k_scanB<<<1, 1024, 0, stream>>>(gh, bbase, bfill, NB, E);
    k_partition<<<(E + CHUNK - 1) / CHUNK, 512, 0, stream>>>(src, dstv, bbase,
                                                             bfill, tmp, E, NB);
    k_bsort<<<NB, 512, 0, stream>>>(tmp, bbase, srec, rs, dinv, N);
    k_wgt<<<(E + 255) / 256, 256, 0, stream>>>(srec, dinv, E);
    k_pullg<<<(N + 15) / 16, 256, 0, stream>>>(rs, srec, dinv, (const uint4*)h,
                                               b1, W2, h2, N);
    k_pull2<<<(N * 4 + 255) / 256, 256, 0, stream>>>(rs, srec, dinv,
                                                     (const uint2*)h2, b2, outp, N);
}